// Round 1
// baseline (1301.386 us; speedup 1.0000x reference)
//
#include <hip/hip_runtime.h>

// CustomTriangleMultiplicationOutgoing — fp32 baseline (round 1)
//
// Pipeline:
//   K1 proj_kernel: z -> LN -> {left, right, go}   (5 GEMMs [147456,128]x[128,128], fused LN+gates+mask)
//   K2 tri_kernel:  zo[c][i][j] = sum_k left[i,k,c]*right[j,k,c]   (128 batched 384^3 GEMMs)
//   K3 out_kernel:  out = (LN_c(zo) @ Wo + bo) * go
//
// Workspace (floats): left[NROW*128] | right[NROW*128] | go[NROW*128] | zo[128*NROW]  = 302 MB
// All fp32 vector-ALU (no fp32 MFMA on CDNA4). Expected compute-bound, ~400-480us.

#define NSEQ 384
#define NROW (384 * 384)

__device__ __forceinline__ float sigmoidf_(float x) {
    return 1.0f / (1.0f + __expf(-x));
}

// ---------------------------------------------------------------------------
// K1: fused LayerNorm + 5 projections.
// Block: 256 threads = (tx 16, ty 16). Tile: 64 rows x 128 cols, K=128.
// LDS: At[k][row] transposed normalized z tile (pad 68), Ws[k][64] half of a W.
// ---------------------------------------------------------------------------
__global__ __launch_bounds__(256) void proj_kernel(
    const float* __restrict__ z, const float* __restrict__ mask,
    const float* __restrict__ ng, const float* __restrict__ nb,
    const float* __restrict__ Wa, const float* __restrict__ ba,
    const float* __restrict__ Wga, const float* __restrict__ bga,
    const float* __restrict__ Wb, const float* __restrict__ bb,
    const float* __restrict__ Wgb, const float* __restrict__ bgb,
    const float* __restrict__ Wgo, const float* __restrict__ bgo,
    float* __restrict__ left, float* __restrict__ right, float* __restrict__ go)
{
    __shared__ float At[128][68];
    __shared__ float Ws[128][64];
    const int t = threadIdx.x;
    const int tx = t & 15, ty = t >> 4;
    const int row0 = blockIdx.x * 64;

    // ---- load z tile [64 rows][128] -> At transposed [k][row] ----
#pragma unroll
    for (int it = 0; it < 8; ++it) {
        const int f = t + it * 256;          // float4 index 0..2047
        const int r = f >> 5;                // 32 float4 per row
        const int c4 = (f & 31) << 2;
        const float4 v = *reinterpret_cast<const float4*>(z + (size_t)(row0 + r) * 128 + c4);
        At[c4 + 0][r] = v.x;
        At[c4 + 1][r] = v.y;
        At[c4 + 2][r] = v.z;
        At[c4 + 3][r] = v.w;
    }
    __syncthreads();

    // ---- LayerNorm per row: 4 lanes per row ----
    {
        const int r = t >> 2, sub = t & 3;
        float s = 0.f, ss = 0.f;
#pragma unroll
        for (int q = 0; q < 32; ++q) {
            const float x = At[sub * 32 + q][r];
            s += x;
            ss += x * x;
        }
        s += __shfl_xor(s, 1);  ss += __shfl_xor(ss, 1);
        s += __shfl_xor(s, 2);  ss += __shfl_xor(ss, 2);
        const float m = s * (1.f / 128.f);
        const float inv = rsqrtf(ss * (1.f / 128.f) - m * m + 1e-5f);
#pragma unroll
        for (int q = 0; q < 32; ++q) {
            const int k = sub * 32 + q;
            At[k][r] = (At[k][r] - m) * inv * ng[k] + nb[k];
        }
    }

    float mk[4];
#pragma unroll
    for (int m = 0; m < 4; ++m) mk[m] = mask[row0 + ty * 4 + m];

    float accA[4][4], accG[4][4];

#define LOAD_W(Wp, h)                                                              \
    __syncthreads();                                                               \
    _Pragma("unroll")                                                              \
    for (int it = 0; it < 8; ++it) {                                               \
        const int f = t + it * 256;                                                \
        const int k = f >> 4;                                                      \
        const int c4 = (f & 15) << 2;                                              \
        *reinterpret_cast<float4*>(&Ws[k][c4]) =                                   \
            *reinterpret_cast<const float4*>((Wp) + k * 128 + (h) * 64 + c4);      \
    }                                                                              \
    __syncthreads();

#define MM(acc)                                                                    \
    _Pragma("unroll")                                                              \
    for (int m = 0; m < 4; ++m)                                                    \
        _Pragma("unroll")                                                          \
        for (int n = 0; n < 4; ++n) (acc)[m][n] = 0.f;                             \
    _Pragma("unroll 8")                                                            \
    for (int k = 0; k < 128; ++k) {                                                \
        const float4 a = *reinterpret_cast<const float4*>(&At[k][ty * 4]);         \
        const float4 b = *reinterpret_cast<const float4*>(&Ws[k][tx * 4]);         \
        const float av[4] = {a.x, a.y, a.z, a.w};                                  \
        const float bv[4] = {b.x, b.y, b.z, b.w};                                  \
        _Pragma("unroll")                                                          \
        for (int m = 0; m < 4; ++m)                                                \
            _Pragma("unroll")                                                      \
            for (int n = 0; n < 4; ++n) (acc)[m][n] = fmaf(av[m], bv[n], (acc)[m][n]); \
    }

    for (int h = 0; h < 2; ++h) {
        const int c0 = h * 64 + tx * 4;

        // left = (zn@Wa+ba) * sigmoid(zn@Wga+bga) * mask
        LOAD_W(Wa, h);  MM(accA);
        LOAD_W(Wga, h); MM(accG);
        {
            const float4 b1 = *reinterpret_cast<const float4*>(ba + c0);
            const float4 b2 = *reinterpret_cast<const float4*>(bga + c0);
#pragma unroll
            for (int m = 0; m < 4; ++m) {
                float4 o;
                o.x = (accA[m][0] + b1.x) * sigmoidf_(accG[m][0] + b2.x) * mk[m];
                o.y = (accA[m][1] + b1.y) * sigmoidf_(accG[m][1] + b2.y) * mk[m];
                o.z = (accA[m][2] + b1.z) * sigmoidf_(accG[m][2] + b2.z) * mk[m];
                o.w = (accA[m][3] + b1.w) * sigmoidf_(accG[m][3] + b2.w) * mk[m];
                *reinterpret_cast<float4*>(left + (size_t)(row0 + ty * 4 + m) * 128 + c0) = o;
            }
        }

        // right = (zn@Wb+bb) * sigmoid(zn@Wgb+bgb) * mask
        LOAD_W(Wb, h);  MM(accA);
        LOAD_W(Wgb, h); MM(accG);
        {
            const float4 b1 = *reinterpret_cast<const float4*>(bb + c0);
            const float4 b2 = *reinterpret_cast<const float4*>(bgb + c0);
#pragma unroll
            for (int m = 0; m < 4; ++m) {
                float4 o;
                o.x = (accA[m][0] + b1.x) * sigmoidf_(accG[m][0] + b2.x) * mk[m];
                o.y = (accA[m][1] + b1.y) * sigmoidf_(accG[m][1] + b2.y) * mk[m];
                o.z = (accA[m][2] + b1.z) * sigmoidf_(accG[m][2] + b2.z) * mk[m];
                o.w = (accA[m][3] + b1.w) * sigmoidf_(accG[m][3] + b2.w) * mk[m];
                *reinterpret_cast<float4*>(right + (size_t)(row0 + ty * 4 + m) * 128 + c0) = o;
            }
        }

        // go = sigmoid(zn@Wgo+bgo)
        LOAD_W(Wgo, h); MM(accA);
        {
            const float4 b1 = *reinterpret_cast<const float4*>(bgo + c0);
#pragma unroll
            for (int m = 0; m < 4; ++m) {
                float4 o;
                o.x = sigmoidf_(accA[m][0] + b1.x);
                o.y = sigmoidf_(accA[m][1] + b1.y);
                o.z = sigmoidf_(accA[m][2] + b1.z);
                o.w = sigmoidf_(accA[m][3] + b1.w);
                *reinterpret_cast<float4*>(go + (size_t)(row0 + ty * 4 + m) * 128 + c0) = o;
            }
        }
    }
#undef LOAD_W
#undef MM
}

// ---------------------------------------------------------------------------
// K2: triangle einsum. zo[c][i*384+j] = sum_k left[i,k,c] * right[j,k,c].
// Grid: (32 c-chunks of 4, 6 i-tiles, 6 j-tiles). Block 256 = 4 c-planes x 64.
// Per thread: acc[8 i][8 j] for one channel. LDS: Lt/Rt [4c][16k][64].
// ---------------------------------------------------------------------------
__global__ __launch_bounds__(256) void tri_kernel(
    const float* __restrict__ left, const float* __restrict__ right,
    float* __restrict__ zo)
{
    __shared__ float Lt[4][16][64];
    __shared__ float Rt[4][16][64];
    const int t = threadIdx.x;
    const int cq = t >> 6;          // 0..3
    const int s = t & 63;
    const int tx = s & 7, ty = s >> 3;   // i = tx*8.., j = ty*8..
    const int c0 = blockIdx.x * 4;
    const int i0 = blockIdx.y * 64;
    const int j0 = blockIdx.z * 64;

    float acc[8][8];
#pragma unroll
    for (int m = 0; m < 8; ++m)
#pragma unroll
        for (int n = 0; n < 8; ++n) acc[m][n] = 0.f;

    for (int kc = 0; kc < NSEQ; kc += 16) {
        __syncthreads();
#pragma unroll
        for (int p = 0; p < 4; ++p) {
            const int f = t + p * 256;     // 0..1023
            const int ii = f & 63;
            const int kk = f >> 6;
            const float4 v = *reinterpret_cast<const float4*>(
                left + ((size_t)(i0 + ii) * NSEQ + kc + kk) * 128 + c0);
            Lt[0][kk][ii] = v.x; Lt[1][kk][ii] = v.y; Lt[2][kk][ii] = v.z; Lt[3][kk][ii] = v.w;
            const float4 w = *reinterpret_cast<const float4*>(
                right + ((size_t)(j0 + ii) * NSEQ + kc + kk) * 128 + c0);
            Rt[0][kk][ii] = w.x; Rt[1][kk][ii] = w.y; Rt[2][kk][ii] = w.z; Rt[3][kk][ii] = w.w;
        }
        __syncthreads();
#pragma unroll
        for (int kk = 0; kk < 16; ++kk) {
            const float4 l0 = *reinterpret_cast<const float4*>(&Lt[cq][kk][tx * 8]);
            const float4 l1 = *reinterpret_cast<const float4*>(&Lt[cq][kk][tx * 8 + 4]);
            const float4 r0 = *reinterpret_cast<const float4*>(&Rt[cq][kk][ty * 8]);
            const float4 r1 = *reinterpret_cast<const float4*>(&Rt[cq][kk][ty * 8 + 4]);
            const float lv[8] = {l0.x, l0.y, l0.z, l0.w, l1.x, l1.y, l1.z, l1.w};
            const float rv[8] = {r0.x, r0.y, r0.z, r0.w, r1.x, r1.y, r1.z, r1.w};
#pragma unroll
            for (int m = 0; m < 8; ++m)
#pragma unroll
                for (int n = 0; n < 8; ++n) acc[m][n] = fmaf(lv[m], rv[n], acc[m][n]);
        }
    }

    // write zo[c][i*384+j], coalesced float4 over j
    float* zp = zo + (size_t)(c0 + cq) * NROW;
#pragma unroll
    for (int m = 0; m < 8; ++m) {
        const size_t base = (size_t)(i0 + tx * 8 + m) * NSEQ + j0 + ty * 8;
        float4 o0 = {acc[m][0], acc[m][1], acc[m][2], acc[m][3]};
        float4 o1 = {acc[m][4], acc[m][5], acc[m][6], acc[m][7]};
        *reinterpret_cast<float4*>(zp + base) = o0;
        *reinterpret_cast<float4*>(zp + base + 4) = o1;
    }
}

// ---------------------------------------------------------------------------
// K3: out = (LN_c(zo) @ Wo + bo) * go.  zo is [c][row] so loads coalesce and
// land directly in the transposed LDS tile At[c][row].
// ---------------------------------------------------------------------------
__global__ __launch_bounds__(256) void out_kernel(
    const float* __restrict__ zo,
    const float* __restrict__ nog, const float* __restrict__ nob,
    const float* __restrict__ Wo, const float* __restrict__ bo,
    const float* __restrict__ go, float* __restrict__ out)
{
    __shared__ float At[128][68];
    __shared__ float Ws[128][64];
    const int t = threadIdx.x;
    const int tx = t & 15, ty = t >> 4;
    const int row0 = blockIdx.x * 64;

    // load zo tile: for each c-plane, 64 consecutive rows
#pragma unroll
    for (int it = 0; it < 8; ++it) {
        const int f = t + it * 256;       // 0..2047 float4s
        const int c = f >> 4;             // 16 float4 per plane-row
        const int j4 = (f & 15) << 2;
        const float4 v = *reinterpret_cast<const float4*>(zo + (size_t)c * NROW + row0 + j4);
        *reinterpret_cast<float4*>(&At[c][j4]) = v;
    }
    __syncthreads();

    // LayerNorm over c per row
    {
        const int r = t >> 2, sub = t & 3;
        float s = 0.f, ss = 0.f;
#pragma unroll
        for (int q = 0; q < 32; ++q) {
            const float x = At[sub * 32 + q][r];
            s += x;
            ss += x * x;
        }
        s += __shfl_xor(s, 1);  ss += __shfl_xor(ss, 1);
        s += __shfl_xor(s, 2);  ss += __shfl_xor(ss, 2);
        const float m = s * (1.f / 128.f);
        const float inv = rsqrtf(ss * (1.f / 128.f) - m * m + 1e-5f);
#pragma unroll
        for (int q = 0; q < 32; ++q) {
            const int k = sub * 32 + q;
            At[k][r] = (At[k][r] - m) * inv * nog[k] + nob[k];
        }
    }

    float accA[4][4];
    for (int h = 0; h < 2; ++h) {
        const int c0 = h * 64 + tx * 4;
        __syncthreads();
#pragma unroll
        for (int it = 0; it < 8; ++it) {
            const int f = t + it * 256;
            const int k = f >> 4;
            const int c4 = (f & 15) << 2;
            *reinterpret_cast<float4*>(&Ws[k][c4]) =
                *reinterpret_cast<const float4*>(Wo + k * 128 + h * 64 + c4);
        }
        __syncthreads();
#pragma unroll
        for (int m = 0; m < 4; ++m)
#pragma unroll
            for (int n = 0; n < 4; ++n) accA[m][n] = 0.f;
#pragma unroll 8
        for (int k = 0; k < 128; ++k) {
            const float4 a = *reinterpret_cast<const float4*>(&At[k][ty * 4]);
            const float4 b = *reinterpret_cast<const float4*>(&Ws[k][tx * 4]);
            const float av[4] = {a.x, a.y, a.z, a.w};
            const float bv[4] = {b.x, b.y, b.z, b.w};
#pragma unroll
            for (int m = 0; m < 4; ++m)
#pragma unroll
                for (int n = 0; n < 4; ++n) accA[m][n] = fmaf(av[m], bv[n], accA[m][n]);
        }
        const float4 b1 = *reinterpret_cast<const float4*>(bo + c0);
#pragma unroll
        for (int m = 0; m < 4; ++m) {
            const size_t base = (size_t)(row0 + ty * 4 + m) * 128 + c0;
            const float4 g = *reinterpret_cast<const float4*>(go + base);
            float4 o;
            o.x = (accA[m][0] + b1.x) * g.x;
            o.y = (accA[m][1] + b1.y) * g.y;
            o.z = (accA[m][2] + b1.z) * g.z;
            o.w = (accA[m][3] + b1.w) * g.w;
            *reinterpret_cast<float4*>(out + base) = o;
        }
    }
}

// ---------------------------------------------------------------------------
extern "C" void kernel_launch(void* const* d_in, const int* in_sizes, int n_in,
                              void* d_out, int out_size, void* d_ws, size_t ws_size,
                              hipStream_t stream)
{
    const float* z    = (const float*)d_in[0];
    const float* mask = (const float*)d_in[1];
    const float* ng   = (const float*)d_in[2];
    const float* nb   = (const float*)d_in[3];
    const float* nog  = (const float*)d_in[4];
    const float* nob  = (const float*)d_in[5];
    const float* Wa   = (const float*)d_in[6];
    const float* ba   = (const float*)d_in[7];
    const float* Wb   = (const float*)d_in[8];
    const float* bb   = (const float*)d_in[9];
    const float* Wga  = (const float*)d_in[10];
    const float* bga  = (const float*)d_in[11];
    const float* Wgb  = (const float*)d_in[12];
    const float* bgb  = (const float*)d_in[13];
    const float* Wo   = (const float*)d_in[14];
    const float* bo   = (const float*)d_in[15];
    const float* Wgo  = (const float*)d_in[16];
    const float* bgo  = (const float*)d_in[17];
    float* outp = (float*)d_out;

    const size_t S = (size_t)NROW * 128;   // 18,874,368
    float* ws    = (float*)d_ws;
    float* left  = ws;
    float* right = ws + S;
    float* go    = ws + 2 * S;
    float* zo    = ws + 3 * S;

    proj_kernel<<<NROW / 64, 256, 0, stream>>>(z, mask, ng, nb, Wa, ba, Wga, bga,
                                               Wb, bb, Wgb, bgb, Wgo, bgo,
                                               left, right, go);
    tri_kernel<<<dim3(32, 6, 6), 256, 0, stream>>>(left, right, zo);
    out_kernel<<<NROW / 64, 256, 0, stream>>>(zo, nog, nob, Wo, bo, go, outp);
}

// Round 5
// 815.171 us; speedup vs baseline: 1.5965x; 1.5965x over previous
//
#include <hip/hip_runtime.h>

// CustomTriangleMultiplicationOutgoing — round 2 kernel, 3rd resubmit
// (rounds 2-4 all died on GPUAcquisitionTimeout; kernel never measured;
//  identical resubmission preserves single-variable attribution)
//
//   K1 proj_kernel: z -> LN -> {leftT, rightT [c][row], go [row][c]}
//   K2 tri_kernel:  zo[c][i*384+j] = sum_k leftT[c][i*384+k]*rightT[c][j*384+k]
//                   (coalesced 64B k-chunk loads; fixes round-1's 2.35GB overfetch)
//   K3 out_kernel:  out = (LN_c(zo) @ Wo + bo) * go
//
// Workspace: leftT | rightT | go | zo, each NROW*128 floats = 302 MB total.

#define NSEQ 384
#define NROW (384 * 384)

__device__ __forceinline__ float sigmoidf_(float x) {
    return 1.0f / (1.0f + __expf(-x));
}

// ---------------------------------------------------------------------------
// K1: fused LayerNorm + 5 projections. Block 256 = (tx 16, ty 16), 64-row tile.
// left/right are transposed to [c][row] through an LDS stage reusing Ws.
// ---------------------------------------------------------------------------
__global__ __launch_bounds__(256) void proj_kernel(
    const float* __restrict__ z, const float* __restrict__ mask,
    const float* __restrict__ ng, const float* __restrict__ nb,
    const float* __restrict__ Wa, const float* __restrict__ ba,
    const float* __restrict__ Wga, const float* __restrict__ bga,
    const float* __restrict__ Wb, const float* __restrict__ bb,
    const float* __restrict__ Wgb, const float* __restrict__ bgb,
    const float* __restrict__ Wgo, const float* __restrict__ bgo,
    float* __restrict__ leftT, float* __restrict__ rightT, float* __restrict__ go)
{
    __shared__ float At[128][68];
    __shared__ float Ws[128][64];          // reused as T[64][65] for transpose stage
    float* Tt = &Ws[0][0];
    const int t = threadIdx.x;
    const int tx = t & 15, ty = t >> 4;
    const int row0 = blockIdx.x * 64;

    // ---- load z tile [64 rows][128] -> At transposed [k][row] ----
#pragma unroll
    for (int it = 0; it < 8; ++it) {
        const int f = t + it * 256;
        const int r = f >> 5;
        const int c4 = (f & 31) << 2;
        const float4 v = *reinterpret_cast<const float4*>(z + (size_t)(row0 + r) * 128 + c4);
        At[c4 + 0][r] = v.x;
        At[c4 + 1][r] = v.y;
        At[c4 + 2][r] = v.z;
        At[c4 + 3][r] = v.w;
    }
    __syncthreads();

    // ---- LayerNorm per row: 4 lanes per row ----
    {
        const int r = t >> 2, sub = t & 3;
        float s = 0.f, ss = 0.f;
#pragma unroll
        for (int q = 0; q < 32; ++q) {
            const float x = At[sub * 32 + q][r];
            s += x;
            ss += x * x;
        }
        s += __shfl_xor(s, 1);  ss += __shfl_xor(ss, 1);
        s += __shfl_xor(s, 2);  ss += __shfl_xor(ss, 2);
        const float m = s * (1.f / 128.f);
        const float inv = rsqrtf(ss * (1.f / 128.f) - m * m + 1e-5f);
#pragma unroll
        for (int q = 0; q < 32; ++q) {
            const int k = sub * 32 + q;
            At[k][r] = (At[k][r] - m) * inv * ng[k] + nb[k];
        }
    }

    float mk[4];
#pragma unroll
    for (int m = 0; m < 4; ++m) mk[m] = mask[row0 + ty * 4 + m];

    float accA[4][4], accG[4][4];

#define LOAD_W(Wp, h)                                                              \
    __syncthreads();                                                               \
    _Pragma("unroll")                                                              \
    for (int it = 0; it < 8; ++it) {                                               \
        const int f = t + it * 256;                                                \
        const int k = f >> 4;                                                      \
        const int c4 = (f & 15) << 2;                                              \
        *reinterpret_cast<float4*>(&Ws[k][c4]) =                                   \
            *reinterpret_cast<const float4*>((Wp) + k * 128 + (h) * 64 + c4);      \
    }                                                                              \
    __syncthreads();

#define MM(acc)                                                                    \
    _Pragma("unroll")                                                              \
    for (int m = 0; m < 4; ++m)                                                    \
        _Pragma("unroll")                                                          \
        for (int n = 0; n < 4; ++n) (acc)[m][n] = 0.f;                             \
    _Pragma("unroll 8")                                                            \
    for (int k = 0; k < 128; ++k) {                                                \
        const float4 a = *reinterpret_cast<const float4*>(&At[k][ty * 4]);         \
        const float4 b = *reinterpret_cast<const float4*>(&Ws[k][tx * 4]);         \
        const float av[4] = {a.x, a.y, a.z, a.w};                                  \
        const float bv[4] = {b.x, b.y, b.z, b.w};                                  \
        _Pragma("unroll")                                                          \
        for (int m = 0; m < 4; ++m)                                                \
            _Pragma("unroll")                                                      \
            for (int n = 0; n < 4; ++n) (acc)[m][n] = fmaf(av[m], bv[n], (acc)[m][n]); \
    }

    // stage gated values into Tt[64c][65] then write plane-major, coalesced
#define STORE_T(dst, h, EXPR_X, EXPR_Y, EXPR_Z, EXPR_W)                            \
    __syncthreads(); /* all MM reads of Ws done */                                 \
    _Pragma("unroll")                                                              \
    for (int m = 0; m < 4; ++m) {                                                  \
        Tt[(tx * 4 + 0) * 65 + ty * 4 + m] = (EXPR_X);                             \
        Tt[(tx * 4 + 1) * 65 + ty * 4 + m] = (EXPR_Y);                             \
        Tt[(tx * 4 + 2) * 65 + ty * 4 + m] = (EXPR_Z);                             \
        Tt[(tx * 4 + 3) * 65 + ty * 4 + m] = (EXPR_W);                             \
    }                                                                              \
    __syncthreads();                                                               \
    _Pragma("unroll")                                                              \
    for (int p = 0; p < 4; ++p) {                                                  \
        const int f = t + p * 256;      /* 0..1023 */                              \
        const int c = f >> 4;           /* local col 0..63 */                      \
        const int r4 = (f & 15) << 2;                                              \
        float4 o;                                                                  \
        o.x = Tt[c * 65 + r4 + 0];                                                 \
        o.y = Tt[c * 65 + r4 + 1];                                                 \
        o.z = Tt[c * 65 + r4 + 2];                                                 \
        o.w = Tt[c * 65 + r4 + 3];                                                 \
        *reinterpret_cast<float4*>((dst) + (size_t)((h) * 64 + c) * NROW + row0 + r4) = o; \
    }

    for (int h = 0; h < 2; ++h) {
        const int c0 = h * 64 + tx * 4;

        // left = (zn@Wa+ba) * sigmoid(zn@Wga+bga) * mask -> leftT [c][row]
        LOAD_W(Wa, h);  MM(accA);
        LOAD_W(Wga, h); MM(accG);
        {
            const float4 b1 = *reinterpret_cast<const float4*>(ba + c0);
            const float4 b2 = *reinterpret_cast<const float4*>(bga + c0);
            STORE_T(leftT, h,
                (accA[m][0] + b1.x) * sigmoidf_(accG[m][0] + b2.x) * mk[m],
                (accA[m][1] + b1.y) * sigmoidf_(accG[m][1] + b2.y) * mk[m],
                (accA[m][2] + b1.z) * sigmoidf_(accG[m][2] + b2.z) * mk[m],
                (accA[m][3] + b1.w) * sigmoidf_(accG[m][3] + b2.w) * mk[m]);
        }

        // right = (zn@Wb+bb) * sigmoid(zn@Wgb+bgb) * mask -> rightT [c][row]
        LOAD_W(Wb, h);  MM(accA);
        LOAD_W(Wgb, h); MM(accG);
        {
            const float4 b1 = *reinterpret_cast<const float4*>(bb + c0);
            const float4 b2 = *reinterpret_cast<const float4*>(bgb + c0);
            STORE_T(rightT, h,
                (accA[m][0] + b1.x) * sigmoidf_(accG[m][0] + b2.x) * mk[m],
                (accA[m][1] + b1.y) * sigmoidf_(accG[m][1] + b2.y) * mk[m],
                (accA[m][2] + b1.z) * sigmoidf_(accG[m][2] + b2.z) * mk[m],
                (accA[m][3] + b1.w) * sigmoidf_(accG[m][3] + b2.w) * mk[m]);
        }

        // go = sigmoid(zn@Wgo+bgo)  (row-major, direct)
        LOAD_W(Wgo, h); MM(accA);
        {
            const float4 b1 = *reinterpret_cast<const float4*>(bgo + c0);
#pragma unroll
            for (int m = 0; m < 4; ++m) {
                float4 o;
                o.x = sigmoidf_(accA[m][0] + b1.x);
                o.y = sigmoidf_(accA[m][1] + b1.y);
                o.z = sigmoidf_(accA[m][2] + b1.z);
                o.w = sigmoidf_(accA[m][3] + b1.w);
                *reinterpret_cast<float4*>(go + (size_t)(row0 + ty * 4 + m) * 128 + c0) = o;
            }
        }
    }
#undef LOAD_W
#undef MM
#undef STORE_T
}

// ---------------------------------------------------------------------------
// K2: zo[c][i*384+j] = sum_k leftT[c][i*384+k] * rightT[c][j*384+k].
// Grid (32 c-chunks, 6 i, 6 j). Block 256 = 4 c-planes x (8 tx i)x(8 ty j).
// Global loads: 64B-contiguous k-chunks per (c,row) — fully coalesced.
// LDS [c][k][i] (pad 68): staging writes 2-way (free), compute reads 2-way.
// ---------------------------------------------------------------------------
__global__ __launch_bounds__(256) void tri_kernel(
    const float* __restrict__ leftT, const float* __restrict__ rightT,
    float* __restrict__ zo)
{
    __shared__ float Lt[4][16][68];
    __shared__ float Rt[4][16][68];
    const int t = threadIdx.x;
    const int cq = t >> 6;
    const int s = t & 63;
    const int tx = s & 7, ty = s >> 3;
    const int c0 = blockIdx.x * 4;
    const int i0 = blockIdx.y * 64;
    const int j0 = blockIdx.z * 64;

    float acc[8][8];
#pragma unroll
    for (int m = 0; m < 8; ++m)
#pragma unroll
        for (int n = 0; n < 8; ++n) acc[m][n] = 0.f;

    for (int kc = 0; kc < NSEQ; kc += 16) {
        __syncthreads();
#pragma unroll
        for (int p = 0; p < 4; ++p) {
            const int f = t + p * 256;          // 0..1023
            const int cc = f >> 8;
            const int rem = f & 255;
            const int ii = rem >> 2;            // 0..63
            const int k4 = (rem & 3) << 2;      // 0,4,8,12
            const float4 v = *reinterpret_cast<const float4*>(
                leftT + (size_t)(c0 + cc) * NROW + (size_t)(i0 + ii) * NSEQ + kc + k4);
            Lt[cc][k4 + 0][ii] = v.x;
            Lt[cc][k4 + 1][ii] = v.y;
            Lt[cc][k4 + 2][ii] = v.z;
            Lt[cc][k4 + 3][ii] = v.w;
            const float4 w = *reinterpret_cast<const float4*>(
                rightT + (size_t)(c0 + cc) * NROW + (size_t)(j0 + ii) * NSEQ + kc + k4);
            Rt[cc][k4 + 0][ii] = w.x;
            Rt[cc][k4 + 1][ii] = w.y;
            Rt[cc][k4 + 2][ii] = w.z;
            Rt[cc][k4 + 3][ii] = w.w;
        }
        __syncthreads();
#pragma unroll
        for (int kk = 0; kk < 16; ++kk) {
            const float4 l0 = *reinterpret_cast<const float4*>(&Lt[cq][kk][tx * 8]);
            const float4 l1 = *reinterpret_cast<const float4*>(&Lt[cq][kk][tx * 8 + 4]);
            const float4 r0 = *reinterpret_cast<const float4*>(&Rt[cq][kk][ty * 8]);
            const float4 r1 = *reinterpret_cast<const float4*>(&Rt[cq][kk][ty * 8 + 4]);
            const float lv[8] = {l0.x, l0.y, l0.z, l0.w, l1.x, l1.y, l1.z, l1.w};
            const float rv[8] = {r0.x, r0.y, r0.z, r0.w, r1.x, r1.y, r1.z, r1.w};
#pragma unroll
            for (int m = 0; m < 8; ++m)
#pragma unroll
                for (int n = 0; n < 8; ++n) acc[m][n] = fmaf(lv[m], rv[n], acc[m][n]);
        }
    }

    float* zp = zo + (size_t)(c0 + cq) * NROW;
#pragma unroll
    for (int m = 0; m < 8; ++m) {
        const size_t base = (size_t)(i0 + tx * 8 + m) * NSEQ + j0 + ty * 8;
        float4 o0 = {acc[m][0], acc[m][1], acc[m][2], acc[m][3]};
        float4 o1 = {acc[m][4], acc[m][5], acc[m][6], acc[m][7]};
        *reinterpret_cast<float4*>(zp + base) = o0;
        *reinterpret_cast<float4*>(zp + base + 4) = o1;
    }
}

// ---------------------------------------------------------------------------
// K3: out = (LN_c(zo) @ Wo + bo) * go.  zo [c][row] reads coalesce into At.
// ---------------------------------------------------------------------------
__global__ __launch_bounds__(256) void out_kernel(
    const float* __restrict__ zo,
    const float* __restrict__ nog, const float* __restrict__ nob,
    const float* __restrict__ Wo, const float* __restrict__ bo,
    const float* __restrict__ go, float* __restrict__ out)
{
    __shared__ float At[128][68];
    __shared__ float Ws[128][64];
    const int t = threadIdx.x;
    const int tx = t & 15, ty = t >> 4;
    const int row0 = blockIdx.x * 64;

#pragma unroll
    for (int it = 0; it < 8; ++it) {
        const int f = t + it * 256;
        const int c = f >> 4;
        const int j4 = (f & 15) << 2;
        const float4 v = *reinterpret_cast<const float4*>(zo + (size_t)c * NROW + row0 + j4);
        *reinterpret_cast<float4*>(&At[c][j4]) = v;
    }
    __syncthreads();

    {
        const int r = t >> 2, sub = t & 3;
        float s = 0.f, ss = 0.f;
#pragma unroll
        for (int q = 0; q < 32; ++q) {
            const float x = At[sub * 32 + q][r];
            s += x;
            ss += x * x;
        }
        s += __shfl_xor(s, 1);  ss += __shfl_xor(ss, 1);
        s += __shfl_xor(s, 2);  ss += __shfl_xor(ss, 2);
        const float m = s * (1.f / 128.f);
        const float inv = rsqrtf(ss * (1.f / 128.f) - m * m + 1e-5f);
#pragma unroll
        for (int q = 0; q < 32; ++q) {
            const int k = sub * 32 + q;
            At[k][r] = (At[k][r] - m) * inv * nog[k] + nob[k];
        }
    }

    float accA[4][4];
    for (int h = 0; h < 2; ++h) {
        const int c0 = h * 64 + tx * 4;
        __syncthreads();
#pragma unroll
        for (int it = 0; it < 8; ++it) {
            const int f = t + it * 256;
            const int k = f >> 4;
            const int c4 = (f & 15) << 2;
            *reinterpret_cast<float4*>(&Ws[k][c4]) =
                *reinterpret_cast<const float4*>(Wo + k * 128 + h * 64 + c4);
        }
        __syncthreads();
#pragma unroll
        for (int m = 0; m < 4; ++m)
#pragma unroll
            for (int n = 0; n < 4; ++n) accA[m][n] = 0.f;
#pragma unroll 8
        for (int k = 0; k < 128; ++k) {
            const float4 a = *reinterpret_cast<const float4*>(&At[k][ty * 4]);
            const float4 b = *reinterpret_cast<const float4*>(&Ws[k][tx * 4]);
            const float av[4] = {a.x, a.y, a.z, a.w};
            const float bv[4] = {b.x, b.y, b.z, b.w};
#pragma unroll
            for (int m = 0; m < 4; ++m)
#pragma unroll
                for (int n = 0; n < 4; ++n) accA[m][n] = fmaf(av[m], bv[n], accA[m][n]);
        }
        const float4 b1 = *reinterpret_cast<const float4*>(bo + c0);
#pragma unroll
        for (int m = 0; m < 4; ++m) {
            const size_t base = (size_t)(row0 + ty * 4 + m) * 128 + c0;
            const float4 g = *reinterpret_cast<const float4*>(go + base);
            float4 o;
            o.x = (accA[m][0] + b1.x) * g.x;
            o.y = (accA[m][1] + b1.y) * g.y;
            o.z = (accA[m][2] + b1.z) * g.z;
            o.w = (accA[m][3] + b1.w) * g.w;
            *reinterpret_cast<float4*>(out + base) = o;
        }
    }
}

// ---------------------------------------------------------------------------
extern "C" void kernel_launch(void* const* d_in, const int* in_sizes, int n_in,
                              void* d_out, int out_size, void* d_ws, size_t ws_size,
                              hipStream_t stream)
{
    const float* z    = (const float*)d_in[0];
    const float* mask = (const float*)d_in[1];
    const float* ng   = (const float*)d_in[2];
    const float* nb   = (const float*)d_in[3];
    const float* nog  = (const float*)d_in[4];
    const float* nob  = (const float*)d_in[5];
    const float* Wa   = (const float*)d_in[6];
    const float* ba   = (const float*)d_in[7];
    const float* Wb   = (const float*)d_in[8];
    const float* bb   = (const float*)d_in[9];
    const float* Wga  = (const float*)d_in[10];
    const float* bga  = (const float*)d_in[11];
    const float* Wgb  = (const float*)d_in[12];
    const float* bgb  = (const float*)d_in[13];
    const float* Wo   = (const float*)d_in[14];
    const float* bo   = (const float*)d_in[15];
    const float* Wgo  = (const float*)d_in[16];
    const float* bgo  = (const float*)d_in[17];
    float* outp = (float*)d_out;

    const size_t S = (size_t)NROW * 128;
    float* ws     = (float*)d_ws;
    float* leftT  = ws;
    float* rightT = ws + S;
    float* go     = ws + 2 * S;
    float* zo     = ws + 3 * S;

    proj_kernel<<<NROW / 64, 256, 0, stream>>>(z, mask, ng, nb, Wa, ba, Wga, bga,
                                               Wb, bb, Wgb, bgb, Wgo, bgo,
                                               leftT, rightT, go);
    tri_kernel<<<dim3(32, 6, 6), 256, 0, stream>>>(leftT, rightT, zo);
    out_kernel<<<NROW / 64, 256, 0, stream>>>(zo, nog, nob, Wo, bo, go, outp);
}

// Round 8
// 655.956 us; speedup vs baseline: 1.9840x; 1.2427x over previous
//
#include <hip/hip_runtime.h>

// CustomTriangleMultiplicationOutgoing — round 6 kernel, 2nd resubmit
// (rounds 6-7 benches died on GPUAcquisitionTimeout; never measured;
//  static audits clean incl. A·B^T operand-fragment check)
//
//   K1 proj_kernel: z -> LN -> {lH,lL,rH,rL bf16 [c][i*384+k], go fp32 [row][c]}
//                   (hi/lo split: hi=bf16(v), lo=bf16(v-hi); ~fp32 accuracy)
//   K2 tri_mfma:    zo[c][i*384+j] = sum_k L*R via 3 MFMA products per tile
//                   (LhRh + LhRl + LlRh; 16x16x32 bf16 MFMA, 128x128 tile/block)
//   K3 out_kernel:  out = (LN_c(zo) @ Wo + bo) * go   (unchanged fp32)
//
// Workspace: go fp32 | zo fp32 | lH,lL,rH,rL ushort = 16*S bytes = 302 MB (S=NROW*128).

#define NSEQ 384
#define NROW (384 * 384)

typedef __attribute__((ext_vector_type(8))) short bf16x8;
typedef __attribute__((ext_vector_type(4))) float f32x4;

__device__ __forceinline__ float sigmoidf_(float x) {
    return 1.0f / (1.0f + __expf(-x));
}
__device__ __forceinline__ unsigned short bf16_rne(float f) {
    unsigned int u = __float_as_uint(f);
    u += 0x7FFFu + ((u >> 16) & 1u);
    return (unsigned short)(u >> 16);
}
__device__ __forceinline__ float bf16_tof(unsigned short h) {
    return __uint_as_float(((unsigned int)h) << 16);
}

// ---------------------------------------------------------------------------
// K1: fused LayerNorm + 5 projections. Block 256 = (tx 16, ty 16), 64-row tile.
// left/right transposed via LDS (Tt reuses Ws) and written as bf16 hi/lo planes.
// ---------------------------------------------------------------------------
__global__ __launch_bounds__(256) void proj_kernel(
    const float* __restrict__ z, const float* __restrict__ mask,
    const float* __restrict__ ng, const float* __restrict__ nb,
    const float* __restrict__ Wa, const float* __restrict__ ba,
    const float* __restrict__ Wga, const float* __restrict__ bga,
    const float* __restrict__ Wb, const float* __restrict__ bb,
    const float* __restrict__ Wgb, const float* __restrict__ bgb,
    const float* __restrict__ Wgo, const float* __restrict__ bgo,
    unsigned short* __restrict__ lH, unsigned short* __restrict__ lL,
    unsigned short* __restrict__ rH, unsigned short* __restrict__ rL,
    float* __restrict__ go)
{
    __shared__ float At[128][68];
    __shared__ float Ws[128][64];          // reused as T[64][65] for transpose stage
    float* Tt = &Ws[0][0];
    const int t = threadIdx.x;
    const int tx = t & 15, ty = t >> 4;
    const int row0 = blockIdx.x * 64;

    // ---- load z tile [64 rows][128] -> At transposed [k][row] ----
#pragma unroll
    for (int it = 0; it < 8; ++it) {
        const int f = t + it * 256;
        const int r = f >> 5;
        const int c4 = (f & 31) << 2;
        const float4 v = *reinterpret_cast<const float4*>(z + (size_t)(row0 + r) * 128 + c4);
        At[c4 + 0][r] = v.x;
        At[c4 + 1][r] = v.y;
        At[c4 + 2][r] = v.z;
        At[c4 + 3][r] = v.w;
    }
    __syncthreads();

    // ---- LayerNorm per row: 4 lanes per row ----
    {
        const int r = t >> 2, sub = t & 3;
        float s = 0.f, ss = 0.f;
#pragma unroll
        for (int q = 0; q < 32; ++q) {
            const float x = At[sub * 32 + q][r];
            s += x;
            ss += x * x;
        }
        s += __shfl_xor(s, 1);  ss += __shfl_xor(ss, 1);
        s += __shfl_xor(s, 2);  ss += __shfl_xor(ss, 2);
        const float m = s * (1.f / 128.f);
        const float inv = rsqrtf(ss * (1.f / 128.f) - m * m + 1e-5f);
#pragma unroll
        for (int q = 0; q < 32; ++q) {
            const int k = sub * 32 + q;
            At[k][r] = (At[k][r] - m) * inv * ng[k] + nb[k];
        }
    }

    float mk[4];
#pragma unroll
    for (int m = 0; m < 4; ++m) mk[m] = mask[row0 + ty * 4 + m];

    float accA[4][4], accG[4][4];

#define LOAD_W(Wp, h)                                                              \
    __syncthreads();                                                               \
    _Pragma("unroll")                                                              \
    for (int it = 0; it < 8; ++it) {                                               \
        const int f = t + it * 256;                                                \
        const int k = f >> 4;                                                      \
        const int c4 = (f & 15) << 2;                                              \
        *reinterpret_cast<float4*>(&Ws[k][c4]) =                                   \
            *reinterpret_cast<const float4*>((Wp) + k * 128 + (h) * 64 + c4);      \
    }                                                                              \
    __syncthreads();

#define MM(acc)                                                                    \
    _Pragma("unroll")                                                              \
    for (int m = 0; m < 4; ++m)                                                    \
        _Pragma("unroll")                                                          \
        for (int n = 0; n < 4; ++n) (acc)[m][n] = 0.f;                             \
    _Pragma("unroll 8")                                                            \
    for (int k = 0; k < 128; ++k) {                                                \
        const float4 a = *reinterpret_cast<const float4*>(&At[k][ty * 4]);         \
        const float4 b = *reinterpret_cast<const float4*>(&Ws[k][tx * 4]);         \
        const float av[4] = {a.x, a.y, a.z, a.w};                                  \
        const float bv[4] = {b.x, b.y, b.z, b.w};                                  \
        _Pragma("unroll")                                                          \
        for (int m = 0; m < 4; ++m)                                                \
            _Pragma("unroll")                                                      \
            for (int n = 0; n < 4; ++n) (acc)[m][n] = fmaf(av[m], bv[n], (acc)[m][n]); \
    }

    // stage gated fp32 values into Tt[64c][65], then write bf16 hi/lo planes
    // [c][row] with fully coalesced 128B-per-c ushort4 stores.
#define STORE_T_BF(dstH, dstL, h, EXPR_X, EXPR_Y, EXPR_Z, EXPR_W)                  \
    __syncthreads(); /* all MM reads of Ws done */                                 \
    _Pragma("unroll")                                                              \
    for (int m = 0; m < 4; ++m) {                                                  \
        Tt[(tx * 4 + 0) * 65 + ty * 4 + m] = (EXPR_X);                             \
        Tt[(tx * 4 + 1) * 65 + ty * 4 + m] = (EXPR_Y);                             \
        Tt[(tx * 4 + 2) * 65 + ty * 4 + m] = (EXPR_Z);                             \
        Tt[(tx * 4 + 3) * 65 + ty * 4 + m] = (EXPR_W);                             \
    }                                                                              \
    __syncthreads();                                                               \
    _Pragma("unroll")                                                              \
    for (int p = 0; p < 4; ++p) {                                                  \
        const int f = t + p * 256;      /* 0..1023 */                              \
        const int c = f >> 4;           /* local col 0..63 */                      \
        const int r4 = (f & 15) << 2;                                              \
        ushort4 hv, lv;                                                            \
        const float v0 = Tt[c * 65 + r4 + 0];                                      \
        const float v1 = Tt[c * 65 + r4 + 1];                                      \
        const float v2 = Tt[c * 65 + r4 + 2];                                      \
        const float v3 = Tt[c * 65 + r4 + 3];                                      \
        hv.x = bf16_rne(v0); lv.x = bf16_rne(v0 - bf16_tof(hv.x));                 \
        hv.y = bf16_rne(v1); lv.y = bf16_rne(v1 - bf16_tof(hv.y));                 \
        hv.z = bf16_rne(v2); lv.z = bf16_rne(v2 - bf16_tof(hv.z));                 \
        hv.w = bf16_rne(v3); lv.w = bf16_rne(v3 - bf16_tof(hv.w));                 \
        const size_t off = (size_t)((h) * 64 + c) * NROW + row0 + r4;              \
        *reinterpret_cast<ushort4*>((dstH) + off) = hv;                            \
        *reinterpret_cast<ushort4*>((dstL) + off) = lv;                            \
    }

    for (int h = 0; h < 2; ++h) {
        const int c0 = h * 64 + tx * 4;

        // left = (zn@Wa+ba) * sigmoid(zn@Wga+bga) * mask -> lH/lL [c][row]
        LOAD_W(Wa, h);  MM(accA);
        LOAD_W(Wga, h); MM(accG);
        {
            const float4 b1 = *reinterpret_cast<const float4*>(ba + c0);
            const float4 b2 = *reinterpret_cast<const float4*>(bga + c0);
            STORE_T_BF(lH, lL, h,
                (accA[m][0] + b1.x) * sigmoidf_(accG[m][0] + b2.x) * mk[m],
                (accA[m][1] + b1.y) * sigmoidf_(accG[m][1] + b2.y) * mk[m],
                (accA[m][2] + b1.z) * sigmoidf_(accG[m][2] + b2.z) * mk[m],
                (accA[m][3] + b1.w) * sigmoidf_(accG[m][3] + b2.w) * mk[m]);
        }

        // right = (zn@Wb+bb) * sigmoid(zn@Wgb+bgb) * mask -> rH/rL [c][row]
        LOAD_W(Wb, h);  MM(accA);
        LOAD_W(Wgb, h); MM(accG);
        {
            const float4 b1 = *reinterpret_cast<const float4*>(bb + c0);
            const float4 b2 = *reinterpret_cast<const float4*>(bgb + c0);
            STORE_T_BF(rH, rL, h,
                (accA[m][0] + b1.x) * sigmoidf_(accG[m][0] + b2.x) * mk[m],
                (accA[m][1] + b1.y) * sigmoidf_(accG[m][1] + b2.y) * mk[m],
                (accA[m][2] + b1.z) * sigmoidf_(accG[m][2] + b2.z) * mk[m],
                (accA[m][3] + b1.w) * sigmoidf_(accG[m][3] + b2.w) * mk[m]);
        }

        // go = sigmoid(zn@Wgo+bgo)  (row-major fp32, direct)
        LOAD_W(Wgo, h); MM(accA);
        {
            const float4 b1 = *reinterpret_cast<const float4*>(bgo + c0);
#pragma unroll
            for (int m = 0; m < 4; ++m) {
                float4 o;
                o.x = sigmoidf_(accA[m][0] + b1.x);
                o.y = sigmoidf_(accA[m][1] + b1.y);
                o.z = sigmoidf_(accA[m][2] + b1.z);
                o.w = sigmoidf_(accA[m][3] + b1.w);
                *reinterpret_cast<float4*>(go + (size_t)(row0 + ty * 4 + m) * 128 + c0) = o;
            }
        }
    }
#undef LOAD_W
#undef MM
#undef STORE_T_BF
}

// ---------------------------------------------------------------------------
// K2: bf16x3 MFMA triangle einsum. Per block: one c-plane, 128x128 (i,j) tile.
// 4 waves, each a 64x64 quadrant = 4x4 MFMA 16x16 tiles; K-chunks of 32.
// L*R ~= Lh*Rh + Lh*Rl + Ll*Rh (fp32-quality accumulation in f32 acc).
// LDS tiles [128][40] ushort (pad 40: fragment b128 reads are 2-way = free).
// A/B fragment: lane l -> row l&15, k = (l>>4)*8 + 0..7 (16B contiguous).
// C/D: col = lane&15, row = (lane>>4)*4 + reg  [guide §3, m89-verified].
// ---------------------------------------------------------------------------
__global__ __launch_bounds__(256) void tri_mfma_kernel(
    const unsigned short* __restrict__ lH, const unsigned short* __restrict__ lL,
    const unsigned short* __restrict__ rH, const unsigned short* __restrict__ rL,
    float* __restrict__ zo)
{
    __shared__ unsigned short Ah[128][40];
    __shared__ unsigned short Al[128][40];
    __shared__ unsigned short Bh[128][40];
    __shared__ unsigned short Bl[128][40];

    const int t = threadIdx.x;
    const int w = t >> 6, l = t & 63;
    const int c  = blockIdx.x;
    const int i0 = blockIdx.y * 128;
    const int j0 = blockIdx.z * 128;
    const int iw = (w >> 1) * 64;
    const int jw = (w & 1) * 64;
    const int lr = l & 15;          // fragment row (A) / col (B)
    const int lk = (l >> 4) * 8;    // fragment k base within chunk

    f32x4 acc[4][4];
#pragma unroll
    for (int m = 0; m < 4; ++m)
#pragma unroll
        for (int n = 0; n < 4; ++n) {
            acc[m][n][0] = 0.f; acc[m][n][1] = 0.f;
            acc[m][n][2] = 0.f; acc[m][n][3] = 0.f;
        }

    const size_t cbase = (size_t)c * NROW;

    for (int kc = 0; kc < NSEQ; kc += 32) {
        __syncthreads();   // previous chunk's ds_reads complete before overwrite
#pragma unroll
        for (int p = 0; p < 2; ++p) {
            const int f = t + p * 256;       // 0..511
            const int row = f >> 2;          // 0..127
            const int seg = (f & 3) * 8;     // ushort offset within 32-k chunk
            const size_t gi = cbase + (size_t)(i0 + row) * NSEQ + kc + seg;
            const size_t gj = cbase + (size_t)(j0 + row) * NSEQ + kc + seg;
            *reinterpret_cast<uint4*>(&Ah[row][seg]) = *reinterpret_cast<const uint4*>(lH + gi);
            *reinterpret_cast<uint4*>(&Al[row][seg]) = *reinterpret_cast<const uint4*>(lL + gi);
            *reinterpret_cast<uint4*>(&Bh[row][seg]) = *reinterpret_cast<const uint4*>(rH + gj);
            *reinterpret_cast<uint4*>(&Bl[row][seg]) = *reinterpret_cast<const uint4*>(rL + gj);
        }
        __syncthreads();

        bf16x8 ah[4], al[4];
#pragma unroll
        for (int m = 0; m < 4; ++m) {
            ah[m] = *reinterpret_cast<const bf16x8*>(&Ah[iw + m * 16 + lr][lk]);
            al[m] = *reinterpret_cast<const bf16x8*>(&Al[iw + m * 16 + lr][lk]);
        }
#pragma unroll
        for (int n = 0; n < 4; ++n) {
            const bf16x8 bh = *reinterpret_cast<const bf16x8*>(&Bh[jw + n * 16 + lr][lk]);
            const bf16x8 bl = *reinterpret_cast<const bf16x8*>(&Bl[jw + n * 16 + lr][lk]);
#pragma unroll
            for (int m = 0; m < 4; ++m) {
                acc[m][n] = __builtin_amdgcn_mfma_f32_16x16x32_bf16(al[m], bh, acc[m][n], 0, 0, 0);
                acc[m][n] = __builtin_amdgcn_mfma_f32_16x16x32_bf16(ah[m], bl, acc[m][n], 0, 0, 0);
                acc[m][n] = __builtin_amdgcn_mfma_f32_16x16x32_bf16(ah[m], bh, acc[m][n], 0, 0, 0);
            }
        }
    }

    // C-write: zo[c][(i0+iw+m*16+(l>>4)*4+r)*384 + j0+jw+n*16+(l&15)]
    float* zp = zo + cbase;
#pragma unroll
    for (int m = 0; m < 4; ++m) {
        const int rb = i0 + iw + m * 16 + (l >> 4) * 4;
#pragma unroll
        for (int n = 0; n < 4; ++n) {
            const int cb = j0 + jw + n * 16 + lr;
#pragma unroll
            for (int r = 0; r < 4; ++r)
                zp[(size_t)(rb + r) * NSEQ + cb] = acc[m][n][r];
        }
    }
}

// ---------------------------------------------------------------------------
// K3: out = (LN_c(zo) @ Wo + bo) * go.  zo [c][row] reads coalesce into At.
// ---------------------------------------------------------------------------
__global__ __launch_bounds__(256) void out_kernel(
    const float* __restrict__ zo,
    const float* __restrict__ nog, const float* __restrict__ nob,
    const float* __restrict__ Wo, const float* __restrict__ bo,
    const float* __restrict__ go, float* __restrict__ out)
{
    __shared__ float At[128][68];
    __shared__ float Ws[128][64];
    const int t = threadIdx.x;
    const int tx = t & 15, ty = t >> 4;
    const int row0 = blockIdx.x * 64;

#pragma unroll
    for (int it = 0; it < 8; ++it) {
        const int f = t + it * 256;
        const int c = f >> 4;
        const int j4 = (f & 15) << 2;
        const float4 v = *reinterpret_cast<const float4*>(zo + (size_t)c * NROW + row0 + j4);
        *reinterpret_cast<float4*>(&At[c][j4]) = v;
    }
    __syncthreads();

    {
        const int r = t >> 2, sub = t & 3;
        float s = 0.f, ss = 0.f;
#pragma unroll
        for (int q = 0; q < 32; ++q) {
            const float x = At[sub * 32 + q][r];
            s += x;
            ss += x * x;
        }
        s += __shfl_xor(s, 1);  ss += __shfl_xor(ss, 1);
        s += __shfl_xor(s, 2);  ss += __shfl_xor(ss, 2);
        const float m = s * (1.f / 128.f);
        const float inv = rsqrtf(ss * (1.f / 128.f) - m * m + 1e-5f);
#pragma unroll
        for (int q = 0; q < 32; ++q) {
            const int k = sub * 32 + q;
            At[k][r] = (At[k][r] - m) * inv * nog[k] + nob[k];
        }
    }

    float accA[4][4];
    for (int h = 0; h < 2; ++h) {
        const int c0 = h * 64 + tx * 4;
        __syncthreads();
#pragma unroll
        for (int it = 0; it < 8; ++it) {
            const int f = t + it * 256;
            const int k = f >> 4;
            const int c4 = (f & 15) << 2;
            *reinterpret_cast<float4*>(&Ws[k][c4]) =
                *reinterpret_cast<const float4*>(Wo + k * 128 + h * 64 + c4);
        }
        __syncthreads();
#pragma unroll
        for (int m = 0; m < 4; ++m)
#pragma unroll
            for (int n = 0; n < 4; ++n) accA[m][n] = 0.f;
#pragma unroll 8
        for (int k = 0; k < 128; ++k) {
            const float4 a = *reinterpret_cast<const float4*>(&At[k][ty * 4]);
            const float4 b = *reinterpret_cast<const float4*>(&Ws[k][tx * 4]);
            const float av[4] = {a.x, a.y, a.z, a.w};
            const float bv[4] = {b.x, b.y, b.z, b.w};
#pragma unroll
            for (int m = 0; m < 4; ++m)
#pragma unroll
                for (int n = 0; n < 4; ++n) accA[m][n] = fmaf(av[m], bv[n], accA[m][n]);
        }
        const float4 b1 = *reinterpret_cast<const float4*>(bo + c0);
#pragma unroll
        for (int m = 0; m < 4; ++m) {
            const size_t base = (size_t)(row0 + ty * 4 + m) * 128 + c0;
            const float4 g = *reinterpret_cast<const float4*>(go + base);
            float4 o;
            o.x = (accA[m][0] + b1.x) * g.x;
            o.y = (accA[m][1] + b1.y) * g.y;
            o.z = (accA[m][2] + b1.z) * g.z;
            o.w = (accA[m][3] + b1.w) * g.w;
            *reinterpret_cast<float4*>(out + base) = o;
        }
    }
}

// ---------------------------------------------------------------------------
extern "C" void kernel_launch(void* const* d_in, const int* in_sizes, int n_in,
                              void* d_out, int out_size, void* d_ws, size_t ws_size,
                              hipStream_t stream)
{
    const float* z    = (const float*)d_in[0];
    const float* mask = (const float*)d_in[1];
    const float* ng   = (const float*)d_in[2];
    const float* nb   = (const float*)d_in[3];
    const float* nog  = (const float*)d_in[4];
    const float* nob  = (const float*)d_in[5];
    const float* Wa   = (const float*)d_in[6];
    const float* ba   = (const float*)d_in[7];
    const float* Wb   = (const float*)d_in[8];
    const float* bb   = (const float*)d_in[9];
    const float* Wga  = (const float*)d_in[10];
    const float* bga  = (const float*)d_in[11];
    const float* Wgb  = (const float*)d_in[12];
    const float* bgb  = (const float*)d_in[13];
    const float* Wo   = (const float*)d_in[14];
    const float* bo   = (const float*)d_in[15];
    const float* Wgo  = (const float*)d_in[16];
    const float* bgo  = (const float*)d_in[17];
    float* outp = (float*)d_out;

    const size_t S = (size_t)NROW * 128;   // elements per plane-set
    float* ws = (float*)d_ws;
    float* go = ws;                                    // S floats
    float* zo = ws + S;                                // S floats
    unsigned short* lH = (unsigned short*)(ws + 2 * S);
    unsigned short* lL = lH + S;
    unsigned short* rH = lH + 2 * S;
    unsigned short* rL = lH + 3 * S;
    // total = 8S + 8S bytes = 16S = 302 MB (same footprint as prior rounds)

    proj_kernel<<<NROW / 64, 256, 0, stream>>>(z, mask, ng, nb, Wa, ba, Wga, bga,
                                               Wb, bb, Wgb, bgb, Wgo, bgo,
                                               lH, lL, rH, rL, go);
    tri_mfma_kernel<<<dim3(128, 3, 3), 256, 0, stream>>>(lH, lL, rH, rL, zo);
    out_kernel<<<NROW / 64, 256, 0, stream>>>(zo, nog, nob, Wo, bo, go, outp);
}

// Round 11
// 535.394 us; speedup vs baseline: 2.4307x; 1.2252x over previous
//
#include <hip/hip_runtime.h>

// CustomTriangleMultiplicationOutgoing — round 9 kernel, 2nd resubmit
// (rounds 9-10 benches died on GPUAcquisitionTimeout; never measured;
//  static audits clean: fragment layouts, LDS alignment, Tt-reuse races)
//
//   K0 prep_kernel: W{a,ga,b,gb,go} fp32 [k][n] -> wt[5][2][n][k] bf16 hi/lo (320KB, in zo region)
//   K1 proj_kernel: z -> in-reg LN -> Zh/Zl LDS -> 5 MFMA GEMMs (3 products each)
//                   -> {lH,lL,rH,rL bf16 [c][row], go fp32 [row][c]}
//   K2 tri_mfma:    zo[c][i*384+j] = sum_k L*R  (unchanged, validated round 8)
//   K3 out_kernel:  out = (LN_c(zo) @ Wo + bo) * go   (unchanged fp32)
//
// Workspace: go fp32 | zo fp32 (wt overlaps head of zo) | lH,lL,rH,rL ushort = 302 MB.

#define NSEQ 384
#define NROW (384 * 384)

typedef __attribute__((ext_vector_type(8))) short bf16x8;
typedef __attribute__((ext_vector_type(4))) float f32x4;

__device__ __forceinline__ float sigmoidf_(float x) {
    return 1.0f / (1.0f + __expf(-x));
}
__device__ __forceinline__ unsigned short bf16_rne(float f) {
    unsigned int u = __float_as_uint(f);
    u += 0x7FFFu + ((u >> 16) & 1u);
    return (unsigned short)(u >> 16);
}
__device__ __forceinline__ float bf16_tof(unsigned short h) {
    return __uint_as_float(((unsigned int)h) << 16);
}

// ---------------------------------------------------------------------------
// K0: weight prep. wt[w][p][n][k] bf16 (p=0 hi, p=1 lo), from W[k][n] fp32.
// Transposed layout = MFMA B-operand fragment order (lane reads row n, 16B of k).
// Grid (5, 128): block = 128 threads (thread k, row n = blockIdx.y).
// ---------------------------------------------------------------------------
__global__ void prep_kernel(const float* __restrict__ Wa, const float* __restrict__ Wga,
                            const float* __restrict__ Wb, const float* __restrict__ Wgb,
                            const float* __restrict__ Wgo, unsigned short* __restrict__ wt)
{
    const int wsel = blockIdx.x;
    const int n = blockIdx.y;
    const int k = threadIdx.x;
    const float* W = (wsel == 0) ? Wa : (wsel == 1) ? Wga : (wsel == 2) ? Wb
                     : (wsel == 3) ? Wgb : Wgo;
    const float v = W[k * 128 + n];
    const unsigned short h = bf16_rne(v);
    const unsigned short lo = bf16_rne(v - bf16_tof(h));
    wt[(size_t)((wsel * 2 + 0) * 128 + n) * 128 + k] = h;
    wt[(size_t)((wsel * 2 + 1) * 128 + n) * 128 + k] = lo;
}

// ---------------------------------------------------------------------------
// K1: MFMA projections. Block 256 = 4 waves; tile 64 rows x 128 cols, K=128.
// LDS layout [kc][64][40] (tri-proven pad). Wave w owns m-tile rows w*16..+15.
// A-fragments hoisted to regs once (shared across all 5 GEMMs).
// Per GEMM-half (N=64): stage W hi/lo -> 4 nt x 4 kc x 3 MFMA per wave.
// Gated epilogue: acc -> Tt fp32 [64c][65] (in Wh slab) -> bf16 hi/lo planes.
// ---------------------------------------------------------------------------
__global__ __launch_bounds__(256) void proj_kernel(
    const float* __restrict__ z, const float* __restrict__ mask,
    const float* __restrict__ ng, const float* __restrict__ nb,
    const unsigned short* __restrict__ wt,
    const float* __restrict__ ba, const float* __restrict__ bga,
    const float* __restrict__ bb, const float* __restrict__ bgb,
    const float* __restrict__ bgo,
    unsigned short* __restrict__ lH, unsigned short* __restrict__ lL,
    unsigned short* __restrict__ rH, unsigned short* __restrict__ rL,
    float* __restrict__ go)
{
    __shared__ unsigned short Zh[4][64][40];
    __shared__ unsigned short Zl[4][64][40];
    __shared__ unsigned short Wh[4][64][40];   // also reused as Tt fp32[64][65] (16.6KB<20.5KB)
    __shared__ unsigned short Wl[4][64][40];

    const int t = threadIdx.x;
    const int w = t >> 6, l = t & 63;
    const int lr = l & 15, g = l >> 4;
    const int lk = g * 8;
    const int row0 = blockIdx.x * 64;

    // ---- phase 1: load 64 z rows, LN in registers, split to Zh/Zl ----
    {
        const int r = t >> 2, sub = t & 3;     // 4 lanes per row, 32 k each
        float v[32];
#pragma unroll
        for (int j = 0; j < 8; ++j) {
            const float4 x = *reinterpret_cast<const float4*>(
                z + (size_t)(row0 + r) * 128 + sub * 32 + j * 4);
            v[j * 4 + 0] = x.x; v[j * 4 + 1] = x.y;
            v[j * 4 + 2] = x.z; v[j * 4 + 3] = x.w;
        }
        float s = 0.f, ss = 0.f;
#pragma unroll
        for (int q = 0; q < 32; ++q) { s += v[q]; ss += v[q] * v[q]; }
        s += __shfl_xor(s, 1);  ss += __shfl_xor(ss, 1);
        s += __shfl_xor(s, 2);  ss += __shfl_xor(ss, 2);
        const float mu = s * (1.f / 128.f);
        const float inv = rsqrtf(ss * (1.f / 128.f) - mu * mu + 1e-5f);
        unsigned short hq[32], lq[32];
#pragma unroll
        for (int q = 0; q < 32; ++q) {
            const int k = sub * 32 + q;
            const float x = (v[q] - mu) * inv * ng[k] + nb[k];
            hq[q] = bf16_rne(x);
            lq[q] = bf16_rne(x - bf16_tof(hq[q]));
        }
#pragma unroll
        for (int j = 0; j < 8; ++j) {
            ushort4 ph = {hq[j*4+0], hq[j*4+1], hq[j*4+2], hq[j*4+3]};
            ushort4 pl = {lq[j*4+0], lq[j*4+1], lq[j*4+2], lq[j*4+3]};
            *reinterpret_cast<ushort4*>(&Zh[sub][r][j * 4]) = ph;
            *reinterpret_cast<ushort4*>(&Zl[sub][r][j * 4]) = pl;
        }
    }
    __syncthreads();

    // ---- hoist A fragments (shared by all 5 GEMMs, both halves) ----
    bf16x8 ah[4], al[4];
#pragma unroll
    for (int kc = 0; kc < 4; ++kc) {
        ah[kc] = *reinterpret_cast<const bf16x8*>(&Zh[kc][w * 16 + lr][lk]);
        al[kc] = *reinterpret_cast<const bf16x8*>(&Zl[kc][w * 16 + lr][lk]);
    }
    float mk[4];
#pragma unroll
    for (int r4 = 0; r4 < 4; ++r4) mk[r4] = mask[row0 + w * 16 + g * 4 + r4];

    f32x4 accA[4], accG[4];

#define STAGE_W(widx, hh)                                                          \
    __syncthreads();                                                               \
    _Pragma("unroll")                                                              \
    for (int it = 0; it < 4; ++it) {                                               \
        const int f = t + it * 256;                                                \
        const int n = f >> 4;                                                      \
        const int k8 = (f & 15) * 8;                                               \
        const int kc = k8 >> 5, ko = k8 & 31;                                      \
        *reinterpret_cast<uint4*>(&Wh[kc][n][ko]) = *reinterpret_cast<const uint4*>(  \
            &wt[(size_t)(((widx) * 2 + 0) * 128 + (hh) * 64 + n) * 128 + k8]);     \
        *reinterpret_cast<uint4*>(&Wl[kc][n][ko]) = *reinterpret_cast<const uint4*>(  \
            &wt[(size_t)(((widx) * 2 + 1) * 128 + (hh) * 64 + n) * 128 + k8]);     \
    }                                                                              \
    __syncthreads();

#define GEMM(acc)                                                                  \
    _Pragma("unroll")                                                              \
    for (int nt = 0; nt < 4; ++nt) {                                               \
        acc[nt][0] = 0.f; acc[nt][1] = 0.f; acc[nt][2] = 0.f; acc[nt][3] = 0.f;    \
    }                                                                              \
    _Pragma("unroll")                                                              \
    for (int kc = 0; kc < 4; ++kc) {                                               \
        _Pragma("unroll")                                                          \
        for (int nt = 0; nt < 4; ++nt) {                                           \
            const bf16x8 bh = *reinterpret_cast<const bf16x8*>(&Wh[kc][nt * 16 + lr][lk]); \
            const bf16x8 bl = *reinterpret_cast<const bf16x8*>(&Wl[kc][nt * 16 + lr][lk]); \
            acc[nt] = __builtin_amdgcn_mfma_f32_16x16x32_bf16(al[kc], bh, acc[nt], 0, 0, 0); \
            acc[nt] = __builtin_amdgcn_mfma_f32_16x16x32_bf16(ah[kc], bl, acc[nt], 0, 0, 0); \
            acc[nt] = __builtin_amdgcn_mfma_f32_16x16x32_bf16(ah[kc], bh, acc[nt], 0, 0, 0); \
        }                                                                          \
    }

    // gated pair epilogue: values -> Tt[c][row] fp32 (in Wh slab) -> bf16 hi/lo global
#define EPI_PAIR(dstH, dstL, bA, bG, hh)                                           \
    __syncthreads(); /* all B-fragment reads of Wh/Wl done */                      \
    {                                                                              \
        float* Tt = reinterpret_cast<float*>(&Wh[0][0][0]);                        \
        _Pragma("unroll")                                                          \
        for (int nt = 0; nt < 4; ++nt) {                                           \
            const int cl = nt * 16 + lr;                                           \
            const float vbA = (bA)[(hh) * 64 + cl];                                \
            const float vbG = (bG)[(hh) * 64 + cl];                                \
            _Pragma("unroll")                                                      \
            for (int r4 = 0; r4 < 4; ++r4) {                                       \
                const int rowl = w * 16 + g * 4 + r4;                              \
                Tt[cl * 65 + rowl] =                                               \
                    (accA[nt][r4] + vbA) * sigmoidf_(accG[nt][r4] + vbG) * mk[r4]; \
            }                                                                      \
        }                                                                          \
        __syncthreads();                                                           \
        _Pragma("unroll")                                                          \
        for (int p = 0; p < 4; ++p) {                                              \
            const int f = t + p * 256;                                             \
            const int c = f >> 4;                                                  \
            const int r4b = (f & 15) * 4;                                          \
            const float v0 = Tt[c * 65 + r4b + 0];                                 \
            const float v1 = Tt[c * 65 + r4b + 1];                                 \
            const float v2 = Tt[c * 65 + r4b + 2];                                 \
            const float v3 = Tt[c * 65 + r4b + 3];                                 \
            ushort4 hv, lv;                                                        \
            hv.x = bf16_rne(v0); lv.x = bf16_rne(v0 - bf16_tof(hv.x));             \
            hv.y = bf16_rne(v1); lv.y = bf16_rne(v1 - bf16_tof(hv.y));             \
            hv.z = bf16_rne(v2); lv.z = bf16_rne(v2 - bf16_tof(hv.z));             \
            hv.w = bf16_rne(v3); lv.w = bf16_rne(v3 - bf16_tof(hv.w));             \
            const size_t off = (size_t)((hh) * 64 + c) * NROW + row0 + r4b;        \
            *reinterpret_cast<ushort4*>((dstH) + off) = hv;                        \
            *reinterpret_cast<ushort4*>((dstL) + off) = lv;                        \
        }                                                                          \
    }

    for (int h = 0; h < 2; ++h) {
        STAGE_W(0, h); GEMM(accA);
        STAGE_W(1, h); GEMM(accG);
        EPI_PAIR(lH, lL, ba, bga, h);

        STAGE_W(2, h); GEMM(accA);
        STAGE_W(3, h); GEMM(accG);
        EPI_PAIR(rH, rL, bb, bgb, h);

        STAGE_W(4, h); GEMM(accA);
        // go = sigmoid(acc + bgo), row-major fp32 direct (16-lane 64B segments)
#pragma unroll
        for (int nt = 0; nt < 4; ++nt) {
            const int cl = nt * 16 + lr;
            const float vb = bgo[h * 64 + cl];
#pragma unroll
            for (int r4 = 0; r4 < 4; ++r4) {
                const int rowl = w * 16 + g * 4 + r4;
                go[(size_t)(row0 + rowl) * 128 + h * 64 + cl] =
                    sigmoidf_(accA[nt][r4] + vb);
            }
        }
    }
#undef STAGE_W
#undef GEMM
#undef EPI_PAIR
}

// ---------------------------------------------------------------------------
// K2: bf16x3 MFMA triangle einsum (unchanged from round 8 — validated).
// ---------------------------------------------------------------------------
__global__ __launch_bounds__(256) void tri_mfma_kernel(
    const unsigned short* __restrict__ lH, const unsigned short* __restrict__ lL,
    const unsigned short* __restrict__ rH, const unsigned short* __restrict__ rL,
    float* __restrict__ zo)
{
    __shared__ unsigned short Ah[128][40];
    __shared__ unsigned short Al[128][40];
    __shared__ unsigned short Bh[128][40];
    __shared__ unsigned short Bl[128][40];

    const int t = threadIdx.x;
    const int w = t >> 6, l = t & 63;
    const int c  = blockIdx.x;
    const int i0 = blockIdx.y * 128;
    const int j0 = blockIdx.z * 128;
    const int iw = (w >> 1) * 64;
    const int jw = (w & 1) * 64;
    const int lr = l & 15;
    const int lk = (l >> 4) * 8;

    f32x4 acc[4][4];
#pragma unroll
    for (int m = 0; m < 4; ++m)
#pragma unroll
        for (int n = 0; n < 4; ++n) {
            acc[m][n][0] = 0.f; acc[m][n][1] = 0.f;
            acc[m][n][2] = 0.f; acc[m][n][3] = 0.f;
        }

    const size_t cbase = (size_t)c * NROW;

    for (int kc = 0; kc < NSEQ; kc += 32) {
        __syncthreads();
#pragma unroll
        for (int p = 0; p < 2; ++p) {
            const int f = t + p * 256;
            const int row = f >> 2;
            const int seg = (f & 3) * 8;
            const size_t gi = cbase + (size_t)(i0 + row) * NSEQ + kc + seg;
            const size_t gj = cbase + (size_t)(j0 + row) * NSEQ + kc + seg;
            *reinterpret_cast<uint4*>(&Ah[row][seg]) = *reinterpret_cast<const uint4*>(lH + gi);
            *reinterpret_cast<uint4*>(&Al[row][seg]) = *reinterpret_cast<const uint4*>(lL + gi);
            *reinterpret_cast<uint4*>(&Bh[row][seg]) = *reinterpret_cast<const uint4*>(rH + gj);
            *reinterpret_cast<uint4*>(&Bl[row][seg]) = *reinterpret_cast<const uint4*>(rL + gj);
        }
        __syncthreads();

        bf16x8 ah[4], al[4];
#pragma unroll
        for (int m = 0; m < 4; ++m) {
            ah[m] = *reinterpret_cast<const bf16x8*>(&Ah[iw + m * 16 + lr][lk]);
            al[m] = *reinterpret_cast<const bf16x8*>(&Al[iw + m * 16 + lr][lk]);
        }
#pragma unroll
        for (int n = 0; n < 4; ++n) {
            const bf16x8 bh = *reinterpret_cast<const bf16x8*>(&Bh[jw + n * 16 + lr][lk]);
            const bf16x8 bl = *reinterpret_cast<const bf16x8*>(&Bl[jw + n * 16 + lr][lk]);
#pragma unroll
            for (int m = 0; m < 4; ++m) {
                acc[m][n] = __builtin_amdgcn_mfma_f32_16x16x32_bf16(al[m], bh, acc[m][n], 0, 0, 0);
                acc[m][n] = __builtin_amdgcn_mfma_f32_16x16x32_bf16(ah[m], bl, acc[m][n], 0, 0, 0);
                acc[m][n] = __builtin_amdgcn_mfma_f32_16x16x32_bf16(ah[m], bh, acc[m][n], 0, 0, 0);
            }
        }
    }

    float* zp = zo + cbase;
#pragma unroll
    for (int m = 0; m < 4; ++m) {
        const int rb = i0 + iw + m * 16 + (l >> 4) * 4;
#pragma unroll
        for (int n = 0; n < 4; ++n) {
            const int cb = j0 + jw + n * 16 + lr;
#pragma unroll
            for (int r = 0; r < 4; ++r)
                zp[(size_t)(rb + r) * NSEQ + cb] = acc[m][n][r];
        }
    }
}

// ---------------------------------------------------------------------------
// K3: out = (LN_c(zo) @ Wo + bo) * go (unchanged fp32).
// ---------------------------------------------------------------------------
__global__ __launch_bounds__(256) void out_kernel(
    const float* __restrict__ zo,
    const float* __restrict__ nog, const float* __restrict__ nob,
    const float* __restrict__ Wo, const float* __restrict__ bo,
    const float* __restrict__ go, float* __restrict__ out)
{
    __shared__ float At[128][68];
    __shared__ float Ws[128][64];
    const int t = threadIdx.x;
    const int tx = t & 15, ty = t >> 4;
    const int row0 = blockIdx.x * 64;

#pragma unroll
    for (int it = 0; it < 8; ++it) {
        const int f = t + it * 256;
        const int c = f >> 4;
        const int j4 = (f & 15) << 2;
        const float4 v = *reinterpret_cast<const float4*>(zo + (size_t)c * NROW + row0 + j4);
        *reinterpret_cast<float4*>(&At[c][j4]) = v;
    }
    __syncthreads();

    {
        const int r = t >> 2, sub = t & 3;
        float s = 0.f, ss = 0.f;
#pragma unroll
        for (int q = 0; q < 32; ++q) {
            const float x = At[sub * 32 + q][r];
            s += x;
            ss += x * x;
        }
        s += __shfl_xor(s, 1);  ss += __shfl_xor(ss, 1);
        s += __shfl_xor(s, 2);  ss += __shfl_xor(ss, 2);
        const float m = s * (1.f / 128.f);
        const float inv = rsqrtf(ss * (1.f / 128.f) - m * m + 1e-5f);
#pragma unroll
        for (int q = 0; q < 32; ++q) {
            const int k = sub * 32 + q;
            At[k][r] = (At[k][r] - m) * inv * nog[k] + nob[k];
        }
    }

    float accA[4][4];
    for (int h = 0; h < 2; ++h) {
        const int c0 = h * 64 + tx * 4;
        __syncthreads();
#pragma unroll
        for (int it = 0; it < 8; ++it) {
            const int f = t + it * 256;
            const int k = f >> 4;
            const int c4 = (f & 15) << 2;
            *reinterpret_cast<float4*>(&Ws[k][c4]) =
                *reinterpret_cast<const float4*>(Wo + k * 128 + h * 64 + c4);
        }
        __syncthreads();
#pragma unroll
        for (int m = 0; m < 4; ++m)
#pragma unroll
            for (int n = 0; n < 4; ++n) accA[m][n] = 0.f;
#pragma unroll 8
        for (int k = 0; k < 128; ++k) {
            const float4 a = *reinterpret_cast<const float4*>(&At[k][ty * 4]);
            const float4 b = *reinterpret_cast<const float4*>(&Ws[k][tx * 4]);
            const float av[4] = {a.x, a.y, a.z, a.w};
            const float bv[4] = {b.x, b.y, b.z, b.w};
#pragma unroll
            for (int m = 0; m < 4; ++m)
#pragma unroll
                for (int n = 0; n < 4; ++n) accA[m][n] = fmaf(av[m], bv[n], accA[m][n]);
        }
        const float4 b1 = *reinterpret_cast<const float4*>(bo + c0);
#pragma unroll
        for (int m = 0; m < 4; ++m) {
            const size_t base = (size_t)(row0 + ty * 4 + m) * 128 + c0;
            const float4 gv = *reinterpret_cast<const float4*>(go + base);
            float4 o;
            o.x = (accA[m][0] + b1.x) * gv.x;
            o.y = (accA[m][1] + b1.y) * gv.y;
            o.z = (accA[m][2] + b1.z) * gv.z;
            o.w = (accA[m][3] + b1.w) * gv.w;
            *reinterpret_cast<float4*>(out + base) = o;
        }
    }
}

// ---------------------------------------------------------------------------
extern "C" void kernel_launch(void* const* d_in, const int* in_sizes, int n_in,
                              void* d_out, int out_size, void* d_ws, size_t ws_size,
                              hipStream_t stream)
{
    const float* z    = (const float*)d_in[0];
    const float* mask = (const float*)d_in[1];
    const float* ng   = (const float*)d_in[2];
    const float* nb   = (const float*)d_in[3];
    const float* nog  = (const float*)d_in[4];
    const float* nob  = (const float*)d_in[5];
    const float* Wa   = (const float*)d_in[6];
    const float* ba   = (const float*)d_in[7];
    const float* Wb   = (const float*)d_in[8];
    const float* bb   = (const float*)d_in[9];
    const float* Wga  = (const float*)d_in[10];
    const float* bga  = (const float*)d_in[11];
    const float* Wgb  = (const float*)d_in[12];
    const float* bgb  = (const float*)d_in[13];
    const float* Wo   = (const float*)d_in[14];
    const float* bo   = (const float*)d_in[15];
    const float* Wgo  = (const float*)d_in[16];
    const float* bgo  = (const float*)d_in[17];
    float* outp = (float*)d_out;

    const size_t S = (size_t)NROW * 128;
    float* ws = (float*)d_ws;
    float* go = ws;                                    // S floats
    float* zo = ws + S;                                // S floats
    unsigned short* wt = (unsigned short*)zo;          // 320 KB, dead before tri writes zo
    unsigned short* lH = (unsigned short*)(ws + 2 * S);
    unsigned short* lL = lH + S;
    unsigned short* rH = lH + 2 * S;
    unsigned short* rL = lH + 3 * S;

    prep_kernel<<<dim3(5, 128), 128, 0, stream>>>(Wa, Wga, Wb, Wgb, Wgo, wt);
    proj_kernel<<<NROW / 64, 256, 0, stream>>>(z, mask, ng, nb, wt,
                                               ba, bga, bb, bgb, bgo,
                                               lH, lL, rH, rL, go);
    tri_mfma_kernel<<<dim3(128, 3, 3), 256, 0, stream>>>(lH, lL, rH, rL, zo);
    out_kernel<<<NROW / 64, 256, 0, stream>>>(zo, nog, nob, Wo, bo, go, outp);
}